// Round 1
// baseline (21908.736 us; speedup 1.0000x reference)
//
#include <hip/hip_runtime.h>
#include <cstddef>

// LSTM: x[64,512,512] f32, kernel[512,4096] f32, rec_kernel[1024,4096] f32,
// bias[4096] f32 -> h_last[64,1024] f32.
// Strategy: persistent kernel, weights stationary in VGPRs (bf16 fragments),
// fused x-projection (K = 512+1024 = 1536), one grid barrier per timestep,
// double-buffered bf16 h in workspace, fp32 cell state in registers.

namespace {
constexpr int cB = 64;
constexpr int cT = 512;
constexpr int cD = 512;
constexpr int cU = 1024;
constexpr int cG = 4096;   // 4*U
constexpr int NKC = 48;    // K/32 = 1536/32
constexpr int NBLK = 256;
constexpr int NT = 256;
}

typedef __attribute__((ext_vector_type(8))) short   short8;
typedef __attribute__((ext_vector_type(8))) __bf16  bf16x8;
typedef __attribute__((ext_vector_type(4))) float   f32x4;

__device__ inline short f2bf(float f) {
  unsigned u = __float_as_uint(f);
  u += 0x7fffu + ((u >> 16) & 1u);   // round-to-nearest-even
  return (short)(u >> 16);
}

__device__ inline f32x4 mfma16(short8 a, short8 b, f32x4 c) {
  return __builtin_amdgcn_mfma_f32_16x16x32_bf16(
      __builtin_bit_cast(bf16x8, a), __builtin_bit_cast(bf16x8, b), c, 0, 0, 0);
}

__device__ inline float sigm(float x) { return 1.0f / (1.0f + __expf(-x)); }
__device__ inline float tanh_(float x) {
  float a = fabsf(x);
  float e = __expf(-2.0f * a);
  float t = (1.0f - e) / (1.0f + e);
  return x < 0.0f ? -t : t;
}

__global__ __launch_bounds__(NT, 1) void lstm_persist(
    const float* __restrict__ x, const float* __restrict__ wk,
    const float* __restrict__ wr, const float* __restrict__ bias,
    float* __restrict__ out, short* __restrict__ xbf,
    short* h0, short* h1, unsigned* cnt, unsigned* flag) {
  const int tid  = threadIdx.x;
  const int wave = tid >> 6;        // = gate id 0..3 (i,f,c,o)
  const int lane = tid & 63;
  const int n    = lane & 15;       // MFMA col within tile / A row m
  const int quad = lane >> 4;
  const int bid  = blockIdx.x;
  const int mt   = bid & 3;         // batch m-tile (16 rows each)
  const int cg   = bid >> 2;        // u-group 0..63 (16 u each)
  const int ub   = cg * 16;

  __shared__ float zsh[16 * 64];    // [row][gate*16 + u]
  __shared__ short hsh[16 * 16];    // h staging for coalesced store

  // ---- phase 0: convert x to bf16 once (grid-stride) ----
  {
    const f32x4* xv = reinterpret_cast<const f32x4*>(x);
    short8* xo = reinterpret_cast<short8*>(xbf);
    const size_t nvec = (size_t)cB * cT * cD / 8;
    for (size_t i = (size_t)bid * NT + tid; i < nvec; i += (size_t)NBLK * NT) {
      f32x4 v0 = xv[2 * i];
      f32x4 v1 = xv[2 * i + 1];
      short8 s;
      s[0] = f2bf(v0[0]); s[1] = f2bf(v0[1]); s[2] = f2bf(v0[2]); s[3] = f2bf(v0[3]);
      s[4] = f2bf(v1[0]); s[5] = f2bf(v1[1]); s[6] = f2bf(v1[2]); s[7] = f2bf(v1[3]);
      xo[i] = s;
    }
  }

  // ---- load time-invariant W fragments into registers ----
  // B-frag layout (16x16x32 bf16): B[k][n], n = lane&15, k = quad*8 + j.
  short8 Bf[NKC];
  {
    const int col = wave * cU + ub + n;     // column in the 4096 gate dim
    #pragma unroll
    for (int kc = 0; kc < NKC; ++kc) {
      const int k0 = kc * 32 + quad * 8;
      short8 b;
      #pragma unroll
      for (int j = 0; j < 8; ++j) {
        const int k = k0 + j;
        const float w = (k < cD) ? wk[(size_t)k * cG + col]
                                 : wr[(size_t)(k - cD) * cG + col];
        b[j] = f2bf(w);
      }
      Bf[kc] = b;
    }
  }

  // gate-phase mapping: thread -> (row, u)
  const int grow = tid >> 4;   // 0..15
  const int gu   = tid & 15;   // 0..15
  const float bi  = bias[0 * cU + ub + gu];
  const float bff = bias[1 * cU + ub + gu];
  const float bc  = bias[2 * cU + ub + gu];
  const float bo  = bias[3 * cU + ub + gu];
  float c = 0.0f;

  // A-frag addressing: A[m][k], m = lane&15 -> batch row, k = quad*8 + j
  const int brow = mt * 16 + n;
  const short* xrow = xbf + (size_t)brow * cT * cD + quad * 8;
  const int hoff = brow * cU + quad * 8;

  auto gbar = [&](unsigned e) {
    __threadfence();
    __syncthreads();
    if (tid == 0) {
      unsigned old = __hip_atomic_fetch_add(cnt, 1u, __ATOMIC_RELAXED,
                                            __HIP_MEMORY_SCOPE_AGENT);
      if (old == e * NBLK - 1u) {
        __hip_atomic_store(flag, e, __ATOMIC_RELEASE, __HIP_MEMORY_SCOPE_AGENT);
      } else {
        while (__hip_atomic_load(flag, __ATOMIC_RELAXED,
                                 __HIP_MEMORY_SCOPE_AGENT) < e)
          __builtin_amdgcn_s_sleep(1);
      }
    }
    __syncthreads();
    __threadfence();
  };

  gbar(1);   // xbf ready everywhere; h0 zeroed by host-side memset

  const short* hp = h0;
  short* hn = h1;

  for (int t = 0; t < cT; ++t) {
    f32x4 acc[4] = {{0,0,0,0},{0,0,0,0},{0,0,0,0},{0,0,0,0}};
    const short* xr = xrow + (size_t)t * cD;
    #pragma unroll
    for (int kc = 0; kc < 16; ++kc) {   // x part of K
      short8 af = *reinterpret_cast<const short8*>(xr + kc * 32);
      acc[kc & 3] = mfma16(af, Bf[kc], acc[kc & 3]);
    }
    const short* hr = hp + hoff;
    #pragma unroll
    for (int kc = 16; kc < NKC; ++kc) { // h part of K
      short8 af = *reinterpret_cast<const short8*>(hr + (kc - 16) * 32);
      acc[kc & 3] = mfma16(af, Bf[kc], acc[kc & 3]);
    }
    f32x4 z4 = (acc[0] + acc[1]) + (acc[2] + acc[3]);

    // C/D layout: col = lane&15, row = quad*4 + reg
    #pragma unroll
    for (int r = 0; r < 4; ++r)
      zsh[(quad * 4 + r) * 64 + wave * 16 + n] = z4[r];
    __syncthreads();

    const float* zr = zsh + grow * 64;
    float ig = sigm(zr[gu]        + bi);
    float fg = sigm(zr[16 + gu]   + bff);
    float gg = tanh_(zr[32 + gu]  + bc);
    float og = sigm(zr[48 + gu]   + bo);
    c = fg * c + ig * gg;
    float h = og * tanh_(c);

    if (t == cT - 1) {
      out[(size_t)(mt * 16 + grow) * cU + ub + gu] = h;
    } else {
      hsh[grow * 16 + gu] = f2bf(h);
      __syncthreads();
      if (tid < 32) {
        const int r = tid >> 1, s = tid & 1;
        *reinterpret_cast<short8*>(hn + (size_t)(mt * 16 + r) * cU + ub + s * 8) =
            *reinterpret_cast<const short8*>(&hsh[r * 16 + s * 8]);
      }
      gbar((unsigned)t + 2u);
      short* tmp = hn; hn = (short*)hp; hp = tmp;
    }
  }
}

extern "C" void kernel_launch(void* const* d_in, const int* in_sizes, int n_in,
                              void* d_out, int out_size, void* d_ws, size_t ws_size,
                              hipStream_t stream) {
  const float* x    = (const float*)d_in[0];
  const float* wk   = (const float*)d_in[1];
  const float* wr   = (const float*)d_in[2];
  const float* bias = (const float*)d_in[3];
  float* out = (float*)d_out;

  char* ws = (char*)d_ws;
  unsigned* cnt  = (unsigned*)ws;              // barrier arrival counter
  unsigned* flag = (unsigned*)(ws + 128);      // barrier epoch flag
  short* h0  = (short*)(ws + 512);             // h buffers: 2 x 64*1024 bf16
  short* h1  = h0 + (size_t)cB * cU;
  short* xbf = (short*)(ws + 512 + 2 * (size_t)cB * cU * 2);  // x in bf16, 32 MB

  // zero: barrier state + h0 (initial hidden state). ws is poisoned 0xAA.
  hipMemsetAsync(ws, 0, 512 + (size_t)cB * cU * 2, stream);

  lstm_persist<<<dim3(NBLK), dim3(NT), 0, stream>>>(
      x, wk, wr, bias, out, xbf, h0, h1, cnt, flag);
}

// Round 2
// 11339.357 us; speedup vs baseline: 1.9321x; 1.9321x over previous
//
#include <hip/hip_runtime.h>
#include <cstddef>

// LSTM: x[64,512,512] f32, kernel[512,4096] f32, rec_kernel[1024,4096] f32,
// bias[4096] f32 -> h_last[64,1024] f32.
// Persistent kernel, weights stationary in VGPRs (bf16), fused x-projection.
// R2: centralized grid barrier (serialized atomic RMW, ~42us/step) replaced by
// distributed per-block epoch flags; consumers poll only their 64-block mt
// group; directional agent fences; x-MFMAs overlap the wait.

namespace {
constexpr int cB = 64;
constexpr int cT = 512;
constexpr int cD = 512;
constexpr int cU = 1024;
constexpr int cG = 4096;   // 4*U
constexpr int NKC = 48;    // K/32 = 1536/32
constexpr int NBLK = 256;
constexpr int NT = 256;
}

typedef __attribute__((ext_vector_type(8))) short   short8;
typedef __attribute__((ext_vector_type(8))) __bf16  bf16x8;
typedef __attribute__((ext_vector_type(4))) float   f32x4;

__device__ inline short f2bf(float f) {
  unsigned u = __float_as_uint(f);
  u += 0x7fffu + ((u >> 16) & 1u);   // round-to-nearest-even
  return (short)(u >> 16);
}

__device__ inline f32x4 mfma16(short8 a, short8 b, f32x4 c) {
  return __builtin_amdgcn_mfma_f32_16x16x32_bf16(
      __builtin_bit_cast(bf16x8, a), __builtin_bit_cast(bf16x8, b), c, 0, 0, 0);
}

__device__ inline float sigm(float x) { return 1.0f / (1.0f + __expf(-x)); }
__device__ inline float tanh_(float x) {
  float a = fabsf(x);
  float e = __expf(-2.0f * a);
  float t = (1.0f - e) / (1.0f + e);
  return x < 0.0f ? -t : t;
}

__global__ __launch_bounds__(NT, 1) void lstm_persist(
    const float* __restrict__ x, const float* __restrict__ wk,
    const float* __restrict__ wr, const float* __restrict__ bias,
    float* __restrict__ out, short* __restrict__ xbf,
    short* h0, short* h1, unsigned* flags) {
  const int tid  = threadIdx.x;
  const int wave = tid >> 6;        // = gate id 0..3 (i,f,c,o)
  const int lane = tid & 63;
  const int n    = lane & 15;       // MFMA col within tile / A row m
  const int quad = lane >> 4;
  const int bid  = blockIdx.x;
  const int mt   = bid & 3;         // batch m-tile (16 rows each)
  const int cg   = bid >> 2;        // u-group 0..63 (16 u each)
  const int ub   = cg * 16;

  __shared__ float zsh[16 * 64];    // [row][gate*16 + u]
  __shared__ short hsh[16 * 16];    // h staging for coalesced store

  // ---- phase 0: convert x to bf16 once (grid-stride) ----
  {
    const f32x4* xv = reinterpret_cast<const f32x4*>(x);
    short8* xo = reinterpret_cast<short8*>(xbf);
    const size_t nvec = (size_t)cB * cT * cD / 8;
    for (size_t i = (size_t)bid * NT + tid; i < nvec; i += (size_t)NBLK * NT) {
      f32x4 v0 = xv[2 * i];
      f32x4 v1 = xv[2 * i + 1];
      short8 s;
      s[0] = f2bf(v0[0]); s[1] = f2bf(v0[1]); s[2] = f2bf(v0[2]); s[3] = f2bf(v0[3]);
      s[4] = f2bf(v1[0]); s[5] = f2bf(v1[1]); s[6] = f2bf(v1[2]); s[7] = f2bf(v1[3]);
      xo[i] = s;
    }
  }

  // ---- load time-invariant W fragments into registers ----
  // B-frag layout (16x16x32 bf16): B[k][n], n = lane&15, k = quad*8 + j.
  short8 Bf[NKC];
  {
    const int col = wave * cU + ub + n;     // column in the 4096 gate dim
    #pragma unroll
    for (int kc = 0; kc < NKC; ++kc) {
      const int k0 = kc * 32 + quad * 8;
      short8 b;
      #pragma unroll
      for (int j = 0; j < 8; ++j) {
        const int k = k0 + j;
        const float w = (k < cD) ? wk[(size_t)k * cG + col]
                                 : wr[(size_t)(k - cD) * cG + col];
        b[j] = f2bf(w);
      }
      Bf[kc] = b;
    }
  }

  // gate-phase mapping: thread -> (row, u)
  const int grow = tid >> 4;   // 0..15
  const int gu   = tid & 15;   // 0..15
  const float bi  = bias[0 * cU + ub + gu];
  const float bff = bias[1 * cU + ub + gu];
  const float bc  = bias[2 * cU + ub + gu];
  const float bo  = bias[3 * cU + ub + gu];
  float c = 0.0f;

  // A-frag addressing: A[m][k], m = lane&15 -> batch row, k = quad*8 + j
  const int brow = mt * 16 + n;
  const short* xrow = xbf + (size_t)brow * cT * cD + quad * 8;
  const int hoff = brow * cU + quad * 8;

  // ---- initial full-grid barrier (epoch 1): xbf ready everywhere ----
  __builtin_amdgcn_fence(__ATOMIC_RELEASE, "agent");
  __syncthreads();
  if (tid == 0)
    __hip_atomic_store(flags + bid * 16, 1u, __ATOMIC_RELEASE,
                       __HIP_MEMORY_SCOPE_AGENT);
  if (wave == 0) {
    #pragma unroll
    for (int j = 0; j < 4; ++j) {
      const unsigned* fp = flags + (j * 64 + lane) * 16;
      while (__hip_atomic_load(fp, __ATOMIC_RELAXED,
                               __HIP_MEMORY_SCOPE_AGENT) < 1u) {}
    }
  }
  __syncthreads();
  __builtin_amdgcn_fence(__ATOMIC_ACQUIRE, "agent");

  const short* hp = h0;
  short* hn = h1;

  for (int t = 0; t < cT; ++t) {
    // x-part of K (h-independent) — overlaps the flag wait below
    f32x4 acc[4] = {{0,0,0,0},{0,0,0,0},{0,0,0,0},{0,0,0,0}};
    const short* xr = xrow + (size_t)t * cD;
    #pragma unroll
    for (int kc = 0; kc < 16; ++kc) {
      short8 af = *reinterpret_cast<const short8*>(xr + kc * 32);
      acc[kc & 3] = mfma16(af, Bf[kc], acc[kc & 3]);
    }

    if (t > 0) {
      // wait for all 64 producers of our mt group to publish h_t (epoch t+1)
      if (wave == 0) {
        const unsigned* fp = flags + ((lane << 2) + mt) * 16;
        const unsigned e = (unsigned)t + 1u;
        while (__hip_atomic_load(fp, __ATOMIC_RELAXED,
                                 __HIP_MEMORY_SCOPE_AGENT) < e) {}
      }
      __syncthreads();
      __builtin_amdgcn_fence(__ATOMIC_ACQUIRE, "agent");
    }

    const short* hr = hp + hoff;
    #pragma unroll
    for (int kc = 16; kc < NKC; ++kc) { // h part of K
      short8 af = *reinterpret_cast<const short8*>(hr + (kc - 16) * 32);
      acc[kc & 3] = mfma16(af, Bf[kc], acc[kc & 3]);
    }
    f32x4 z4 = (acc[0] + acc[1]) + (acc[2] + acc[3]);

    // C/D layout: col = lane&15, row = quad*4 + reg
    #pragma unroll
    for (int r = 0; r < 4; ++r)
      zsh[(quad * 4 + r) * 64 + wave * 16 + n] = z4[r];
    __syncthreads();

    const float* zr = zsh + grow * 64;
    float ig = sigm(zr[gu]        + bi);
    float fg = sigm(zr[16 + gu]   + bff);
    float gg = tanh_(zr[32 + gu]  + bc);
    float og = sigm(zr[48 + gu]   + bo);
    c = fg * c + ig * gg;
    float h = og * tanh_(c);

    if (t == cT - 1) {
      out[(size_t)(mt * 16 + grow) * cU + ub + gu] = h;
    } else {
      hsh[grow * 16 + gu] = f2bf(h);
      __syncthreads();
      if (tid < 32) {
        const int r = tid >> 1, s = tid & 1;
        *reinterpret_cast<short8*>(hn + (size_t)(mt * 16 + r) * cU + ub + s * 8) =
            *reinterpret_cast<const short8*>(&hsh[r * 16 + s * 8]);
      }
      // publish: writers are all in wave 0, so in-wave vmcnt ordering +
      // release fence suffices before the flag store (no extra barrier).
      if (wave == 0) {
        __builtin_amdgcn_fence(__ATOMIC_RELEASE, "agent");
        if (lane == 0)
          __hip_atomic_store(flags + bid * 16, (unsigned)(t + 2),
                             __ATOMIC_RELEASE, __HIP_MEMORY_SCOPE_AGENT);
      }
      short* tmp = hn; hn = (short*)hp; hp = tmp;
    }
  }
}

extern "C" void kernel_launch(void* const* d_in, const int* in_sizes, int n_in,
                              void* d_out, int out_size, void* d_ws, size_t ws_size,
                              hipStream_t stream) {
  const float* x    = (const float*)d_in[0];
  const float* wk   = (const float*)d_in[1];
  const float* wr   = (const float*)d_in[2];
  const float* bias = (const float*)d_in[3];
  float* out = (float*)d_out;

  char* ws = (char*)d_ws;
  unsigned* flags = (unsigned*)ws;                     // 256 slots x 64B = 16 KB
  short* h0  = (short*)(ws + 16384);                   // 2 x 64*1024 bf16
  short* h1  = h0 + (size_t)cB * cU;
  short* xbf = (short*)(ws + 16384 + 2 * (size_t)cB * cU * 2);  // x bf16, 32 MB

  // zero: flags + h0 (initial hidden state). ws is poisoned 0xAA each call.
  hipMemsetAsync(ws, 0, 16384 + (size_t)cB * cU * 2, stream);

  lstm_persist<<<dim3(NBLK), dim3(NT), 0, stream>>>(
      x, wk, wr, bias, out, xbf, h0, h1, flags);
}

// Round 3
// 2820.099 us; speedup vs baseline: 7.7688x; 4.0209x over previous
//
#include <hip/hip_runtime.h>
#include <cstddef>

// LSTM: x[64,512,512] f32, kernel[512,4096] f32, rec_kernel[1024,4096] f32,
// bias[4096] f32 -> h_last[64,1024] f32.
// Persistent kernel, weights stationary in VGPRs (bf16), fused x-projection.
// R3: fence-free steady state. All cross-block h/flag traffic uses relaxed
// agent-scope atomics (sc0 sc1 -> MALL-coherent, no buffer_wbl2/buffer_inv
// per step). h staged into padded LDS once per block (4x less MALL traffic).
// zsh padded to 65 (was a 16-way bank conflict).

namespace {
constexpr int cB = 64;
constexpr int cT = 512;
constexpr int cD = 512;
constexpr int cU = 1024;
constexpr int cG = 4096;   // 4*U
constexpr int NKC = 48;    // K/32 = 1536/32
constexpr int NBLK = 256;
constexpr int NT = 256;
constexpr int HSTR = 1032; // padded LDS h-row stride (bf16): 516 dwords, %32==4
}

typedef __attribute__((ext_vector_type(8))) short   short8;
typedef __attribute__((ext_vector_type(8))) __bf16  bf16x8;
typedef __attribute__((ext_vector_type(4))) float   f32x4;

__device__ inline short f2bf(float f) {
  unsigned u = __float_as_uint(f);
  u += 0x7fffu + ((u >> 16) & 1u);   // round-to-nearest-even
  return (short)(u >> 16);
}

__device__ inline f32x4 mfma16(short8 a, short8 b, f32x4 c) {
  return __builtin_amdgcn_mfma_f32_16x16x32_bf16(
      __builtin_bit_cast(bf16x8, a), __builtin_bit_cast(bf16x8, b), c, 0, 0, 0);
}

__device__ inline float sigm(float x) { return 1.0f / (1.0f + __expf(-x)); }
__device__ inline float tanh_(float x) {
  float a = fabsf(x);
  float e = __expf(-2.0f * a);
  float t = (1.0f - e) / (1.0f + e);
  return x < 0.0f ? -t : t;
}

__global__ __launch_bounds__(NT, 1) void lstm_persist(
    const float* __restrict__ x, const float* __restrict__ wk,
    const float* __restrict__ wr, const float* __restrict__ bias,
    float* __restrict__ out, short* __restrict__ xbf,
    short* h0, short* h1, unsigned* flags) {
  const int tid  = threadIdx.x;
  const int wave = tid >> 6;        // = gate id 0..3 (i,f,c,o)
  const int lane = tid & 63;
  const int n    = lane & 15;       // MFMA col within tile / A row m
  const int quad = lane >> 4;
  const int bid  = blockIdx.x;
  const int mt   = bid & 3;         // batch m-tile (16 rows each)
  const int cg   = bid >> 2;        // u-group 0..63 (16 u each)
  const int ub   = cg * 16;

  __shared__ short hlds[16 * HSTR]; // staged h rows (padded, ~33 KB)
  __shared__ float zsh[16 * 65];    // [row][gate*16+u], pad 65 = conflict-free
  __shared__ short hsh[16 * 16];    // h staging for coalesced store

  // ---- phase 0: convert x to bf16 once (grid-stride) ----
  {
    const f32x4* xv = reinterpret_cast<const f32x4*>(x);
    short8* xo = reinterpret_cast<short8*>(xbf);
    const size_t nvec = (size_t)cB * cT * cD / 8;
    for (size_t i = (size_t)bid * NT + tid; i < nvec; i += (size_t)NBLK * NT) {
      f32x4 v0 = xv[2 * i];
      f32x4 v1 = xv[2 * i + 1];
      short8 s;
      s[0] = f2bf(v0[0]); s[1] = f2bf(v0[1]); s[2] = f2bf(v0[2]); s[3] = f2bf(v0[3]);
      s[4] = f2bf(v1[0]); s[5] = f2bf(v1[1]); s[6] = f2bf(v1[2]); s[7] = f2bf(v1[3]);
      xo[i] = s;
    }
  }

  // ---- load time-invariant W fragments into registers ----
  // B-frag layout (16x16x32 bf16): B[k][n], n = lane&15, k = quad*8 + j.
  short8 Bf[NKC];
  {
    const int col = wave * cU + ub + n;     // column in the 4096 gate dim
    #pragma unroll
    for (int kc = 0; kc < NKC; ++kc) {
      const int k0 = kc * 32 + quad * 8;
      short8 b;
      #pragma unroll
      for (int j = 0; j < 8; ++j) {
        const int k = k0 + j;
        const float w = (k < cD) ? wk[(size_t)k * cG + col]
                                 : wr[(size_t)(k - cD) * cG + col];
        b[j] = f2bf(w);
      }
      Bf[kc] = b;
    }
  }

  // gate-phase mapping: thread -> (row, u)
  const int grow = tid >> 4;   // 0..15
  const int gu   = tid & 15;   // 0..15
  const float bi  = bias[0 * cU + ub + gu];
  const float bff = bias[1 * cU + ub + gu];
  const float bc  = bias[2 * cU + ub + gu];
  const float bo  = bias[3 * cU + ub + gu];
  float c = 0.0f;

  // A-frag addressing for x: A[m][k], m = lane&15 -> batch row, k = quad*8+j
  const int brow = mt * 16 + n;
  const short* xrow = xbf + (size_t)brow * cT * cD + quad * 8;

  // ---- initial full-grid barrier (epoch 1): xbf ready everywhere ----
  // One-time fences are fine; the steady-state loop below is fence-free.
  __builtin_amdgcn_fence(__ATOMIC_RELEASE, "agent");
  __syncthreads();
  if (tid == 0)
    __hip_atomic_store(flags + bid * 16, 1u, __ATOMIC_RELEASE,
                       __HIP_MEMORY_SCOPE_AGENT);
  if (wave == 0) {
    #pragma unroll
    for (int j = 0; j < 4; ++j) {
      const unsigned* fp = flags + (j * 64 + lane) * 16;
      while (__hip_atomic_load(fp, __ATOMIC_RELAXED,
                               __HIP_MEMORY_SCOPE_AGENT) < 1u) {}
    }
  }
  __syncthreads();
  __builtin_amdgcn_fence(__ATOMIC_ACQUIRE, "agent");

  const unsigned long long* hp64 = (const unsigned long long*)h0;
  unsigned long long* hn64 = (unsigned long long*)h1;
  unsigned long long* hlds64 = (unsigned long long*)hlds;

  for (int t = 0; t < cT; ++t) {
    // x-part of K (h-independent) — overlaps the flag wait below
    f32x4 acc[4] = {{0,0,0,0},{0,0,0,0},{0,0,0,0},{0,0,0,0}};
    const short* xr = xrow + (size_t)t * cD;
    #pragma unroll
    for (int kc = 0; kc < 16; ++kc) {
      short8 af = *reinterpret_cast<const short8*>(xr + kc * 32);
      acc[kc & 3] = mfma16(af, Bf[kc], acc[kc & 3]);
    }

    if (t > 0) {
      // wait for all 64 producers of our mt group to publish h_t
      if (wave == 0) {
        const unsigned* fp = flags + ((lane << 2) + mt) * 16;
        const unsigned e = (unsigned)t + 1u;
        while (__hip_atomic_load(fp, __ATOMIC_RELAXED,
                                 __HIP_MEMORY_SCOPE_AGENT) < e) {}
      }
      __syncthreads();
    }

    // stage our 16 h rows (32 KB) into LDS via MALL-coherent 8B loads:
    // round r covers row mt*16+r; thread tid loads chunk tid (256 chunks/row)
    {
      unsigned long long tmp[16];
      const unsigned long long* src = hp64 + (size_t)(mt * 16) * 256 + tid;
      #pragma unroll
      for (int r = 0; r < 16; ++r)
        tmp[r] = __hip_atomic_load(src + r * 256, __ATOMIC_RELAXED,
                                   __HIP_MEMORY_SCOPE_AGENT);
      unsigned long long* dst = hlds64 + tid;   // row stride 258 (8B units)
      #pragma unroll
      for (int r = 0; r < 16; ++r) dst[r * 258] = tmp[r];
    }
    __syncthreads();

    // h-part MFMAs from LDS (A row = n, k = kc*32 + quad*8 + j)
    const short* hfrag = hlds + n * HSTR + quad * 8;
    #pragma unroll
    for (int kc = 0; kc < 32; ++kc) {
      short8 af = *reinterpret_cast<const short8*>(hfrag + kc * 32);
      acc[kc & 3] = mfma16(af, Bf[16 + kc], acc[kc & 3]);
    }
    f32x4 z4 = (acc[0] + acc[1]) + (acc[2] + acc[3]);

    // C/D layout: col = lane&15, row = quad*4 + reg
    #pragma unroll
    for (int r = 0; r < 4; ++r)
      zsh[(quad * 4 + r) * 65 + wave * 16 + n] = z4[r];
    __syncthreads();

    const float* zr = zsh + grow * 65;
    float ig = sigm(zr[gu]        + bi);
    float fg = sigm(zr[16 + gu]   + bff);
    float gg = tanh_(zr[32 + gu]  + bc);
    float og = sigm(zr[48 + gu]   + bo);
    c = fg * c + ig * gg;
    float h = og * tanh_(c);

    if (t == cT - 1) {
      out[(size_t)(mt * 16 + grow) * cU + ub + gu] = h;
    } else {
      hsh[grow * 16 + gu] = f2bf(h);
      __syncthreads();
      if (wave == 0) {
        // 64 lanes store the block's 16x16 h slice as 8B coherent stores
        const int r = lane >> 2, cc = lane & 3;
        unsigned long long v =
            *reinterpret_cast<const unsigned long long*>(&hsh[r * 16 + cc * 4]);
        __hip_atomic_store(hn64 + (size_t)(mt * 16 + r) * 256 + cg * 4 + cc, v,
                           __ATOMIC_RELAXED, __HIP_MEMORY_SCOPE_AGENT);
        // drain stores to the coherency point, then publish the flag.
        asm volatile("s_waitcnt vmcnt(0)" ::: "memory");
        if (lane == 0)
          __hip_atomic_store(flags + bid * 16, (unsigned)(t + 2),
                             __ATOMIC_RELAXED, __HIP_MEMORY_SCOPE_AGENT);
      }
      const unsigned long long* tmp = hn64;
      hn64 = (unsigned long long*)hp64;
      hp64 = tmp;
    }
  }
}

extern "C" void kernel_launch(void* const* d_in, const int* in_sizes, int n_in,
                              void* d_out, int out_size, void* d_ws, size_t ws_size,
                              hipStream_t stream) {
  const float* x    = (const float*)d_in[0];
  const float* wk   = (const float*)d_in[1];
  const float* wr   = (const float*)d_in[2];
  const float* bias = (const float*)d_in[3];
  float* out = (float*)d_out;

  char* ws = (char*)d_ws;
  unsigned* flags = (unsigned*)ws;                     // 256 slots x 64B = 16 KB
  short* h0  = (short*)(ws + 16384);                   // 2 x 64*1024 bf16
  short* h1  = h0 + (size_t)cB * cU;
  short* xbf = (short*)(ws + 16384 + 2 * (size_t)cB * cU * 2);  // x bf16, 32 MB

  // zero: flags + h0 (initial hidden state). ws is poisoned 0xAA each call.
  hipMemsetAsync(ws, 0, 16384 + (size_t)cB * cU * 2, stream);

  lstm_persist<<<dim3(NBLK), dim3(NT), 0, stream>>>(
      x, wk, wr, bias, out, xbf, h0, h1, flags);
}